// Round 1
// 126.241 us; speedup vs baseline: 1.0407x; 1.0407x over previous
//
#include <hip/hip_runtime.h>
#include <math.h>

// QGRUCell — Round 8: BM=128 main kernel (wave tile 64x32/gate, merged r/i
// accumulators: 4 chains x 2 mfrag = 128 acc VGPRs), counted-vmcnt dual-raw-
// barrier pipeline (10 loads in flight across every barrier), setprio around
// MFMA cluster, XCD-bijective block swizzle (each XCD owns 8 A-panels x 8 n).
// cvt pre-pass split over K halves: 608 -> 1216 blocks (was ~2.4 blocks/CU,
// latency-bound). ws layout unchanged: 512-f16 chunks, A: arr*8192+M32*32+K16,
// W: 16384+(g*16+N32)*32+K16; chunk pos(row,k)=(k>>3&1)*256+row*8+(k&7).

typedef _Float16 f16x8  __attribute__((ext_vector_type(8)));
typedef _Float16 f16x4  __attribute__((ext_vector_type(4)));
typedef __bf16   bf16x8 __attribute__((ext_vector_type(8)));
typedef float    f32x16 __attribute__((ext_vector_type(16)));

namespace {

constexpr int Bsz = 8192, Ksz = 512, Hsz = 512;
constexpr int BM = 64, BN = 64;          // fallback kernel tile

constexpr unsigned WCH0    = 16384u;
constexpr unsigned NCHUNK  = 16384u + 3072u;          // 19456
constexpr unsigned WS_F16  = NCHUNK * 512u;           // 9,961,472 f16
constexpr size_t   WS_NEED = (size_t)WS_F16 * 2;      // 19,922,944 B

__device__ __forceinline__ float qround(float x, float s, float invs) {
    return floorf(x * s + 0.5f) * invs;
}

__device__ __forceinline__ float qsigmoid_dev(float x) {
    float iq = floorf(x * 134217728.0f + 0.5f);
    iq = fminf(fmaxf(iq, -2147483648.0f), 2147483648.0f);
    float e = __expf(-iq * 7.450580596923828125e-9f);
    float s = __builtin_amdgcn_rcpf(1.0f + e);
    float q31 = floorf(s * 2147483648.0f + 0.5f);
    float q15 = floorf(q31 * 1.52587890625e-5f + 0.5f);
    return q15 * 3.0517578125e-5f;
}

__device__ __forceinline__ float qtanh_dev(float x) {
    float iq = floorf(x * 134217728.0f + 0.5f);
    iq = fminf(fmaxf(iq, -2147483648.0f), 2147483648.0f);
    float z = iq * 7.450580596923828125e-9f;
    float e = __expf(2.0f * z);
    float t = 1.0f - 2.0f * __builtin_amdgcn_rcpf(e + 1.0f);
    float q31 = floorf(t * 2147483648.0f + 0.5f);
    float q15 = floorf(q31 * 1.52587890625e-5f + 0.5f);
    return q15 * 3.0517578125e-5f;
}

__device__ __forceinline__ void dma16(const void* g, void* l) {
    __builtin_amdgcn_global_load_lds(
        (const __attribute__((address_space(1))) unsigned int*)g,
        (__attribute__((address_space(3))) unsigned int*)l, 16, 0, 0);
}

__device__ __forceinline__ void split2(float a, float b, unsigned& hi, unsigned& lo) {
    unsigned ua = __float_as_uint(a); ua += 0x7fffu + ((ua >> 16) & 1u);
    unsigned ub = __float_as_uint(b); ub += 0x7fffu + ((ub >> 16) & 1u);
    hi = (ua >> 16) | (ub & 0xffff0000u);
    float ra = a - __uint_as_float(ua & 0xffff0000u);
    float rb = b - __uint_as_float(ub & 0xffff0000u);
    unsigned va = __float_as_uint(ra); va += 0x7fffu + ((va >> 16) & 1u);
    unsigned vb = __float_as_uint(rb); vb += 0x7fffu + ((vb >> 16) & 1u);
    lo = (va >> 16) | (vb & 0xffff0000u);
}

} // namespace

// ---------------- pre-pass: LDS-tile-transpose fp32 -> f16 chunks ----------
// Split over K halves: block b2 = 2*group + khalf handles 32 rows x 256 cols.
// Same swizzle algebra as R7 (khalf*32 == 0 mod 32 so rsw formulas identical).
__global__ __launch_bounds__(256) void cvt_lds_f16(
    const float* __restrict__ x, const float* __restrict__ h,
    const float* __restrict__ wih, const float* __restrict__ whh,
    _Float16* __restrict__ ws)
{
    __shared__ __align__(16) _Float16 lt[8192];   // 16 KB

    const int b2  = blockIdx.x;
    const int b   = b2 >> 1;
    const int kha = b2 & 1;
    const int tid = threadIdx.x;

    const float* src;      // base of the 32-row group (row-major, stride 512)
    unsigned chbase;       // first chunk index of this group
    if (b < 512) {                         // A: x (arr0), h (arr1)
        const int arr = b >> 8, M32 = b & 255;
        src = (arr ? h : x) + (size_t)M32 * 32u * 512u;
        chbase = (unsigned)arr * 8192u + (unsigned)M32 * 32u;
    } else {                               // W: gate g, col-group N32
        const int w = b - 512;             // 0..95
        const int g = w >> 4, N32 = w & 15;
        const int rowLocal = (g % 3) * 512 + N32 * 32;
        src = (g < 3 ? wih : whh) + (size_t)rowLocal * 512u;
        chbase = WCH0 + (unsigned)((g * 16 + N32) * 32);
    }
    src += kha * 256;                      // K-half column offset

    // Phase 1: 8 reps x 256 threads covering 32 rows x 64 float4s
#pragma unroll
    for (int rep = 0; rep < 8; ++rep) {
        const int idx = rep * 256 + tid;       // 0..2047
        const int row = idx >> 6;              // 0..31
        const int q   = idx & 63;              // local float4 col
        const float4 v = *(const float4*)(src + (size_t)row * 512 + q * 4);
        const int K16l = q >> 2;               // 0..15
        const int kh   = (q >> 1) & 1;
        const int half = (q & 1) * 4;
        const int rsw  = (row + (q >> 1)) & 31;
        f16x4 o;
        o[0] = (_Float16)v.x; o[1] = (_Float16)v.y;
        o[2] = (_Float16)v.z; o[3] = (_Float16)v.w;
        *(f16x4*)&lt[K16l * 512 + kh * 256 + rsw * 8 + half] = o;
    }
    __syncthreads();

    // Phase 2: wave w writes chunks K16l = w*4 .. w*4+3
    const int wid = tid >> 6, lane = tid & 63;
    const int kh  = lane >> 5, row = lane & 31;
#pragma unroll
    for (int cc = 0; cc < 4; ++cc) {
        const int K16l = wid * 4 + cc;
        const int rsw  = (row + 2 * K16l + kh) & 31;   // == (row+2*K16g+kh)&31
        const f16x8 o = *(const f16x8*)&lt[K16l * 512 + kh * 256 + rsw * 8];
        *(f16x8*)(ws + (size_t)(chbase + (unsigned)(kha * 16 + K16l)) * 512u
                      + lane * 8) = o;
    }
}

// ---------------- main: BM=128, counted-vmcnt dual-barrier pipeline --------
__global__ __launch_bounds__(256, 2) void qgru_f16_dma3(
    const _Float16* __restrict__ ws, const float* __restrict__ hid,
    const float* __restrict__ bih, const float* __restrict__ bhh,
    float* __restrict__ out)
{
    __shared__ __align__(16) _Float16 lds[40960];   // 80 KB = 2 slabs x 40 KB

    const int t = threadIdx.x, lane = t & 63, wid = t >> 6;
    const int mt = wid >> 1, nt = wid & 1;

    // XCD-bijective swizzle: 512 blocks, xcd = bid%8 owns x-panels {xcd+8i}.
    const int bid = blockIdx.x;
    const int xcd = bid & 7, j = bid >> 3;
    const int xw  = xcd + 8 * (j & 7);     // 0..63
    const int yw  = j >> 3;                // 0..7
    const int m0  = xw * 128, n0 = yw * 64;

    // 40 chunks/step, 10 per wave: first 16 A (arr,m32,ks2), then 24 W.
    unsigned goff[10];
    int      ldst[10];
#pragma unroll
    for (int c = 0; c < 10; ++c) {
        const int gi = wid * 10 + c;
        unsigned ch; int lo;
        if (gi < 16) {
            const int arr = gi >> 3, m32 = (gi >> 1) & 3, ks2 = gi & 1;
            ch = (unsigned)arr * 8192u
               + (unsigned)((m0 >> 5) + m32) * 32u + (unsigned)ks2;
            lo = ((arr * 4 + m32) * 2 + ks2) * 512;
        } else {
            const int bb = gi - 16;
            const int g = bb >> 2, n32 = (bb >> 1) & 1, ks2 = bb & 1;
            ch = WCH0 + (unsigned)((g * 16 + (n0 >> 5) + n32) * 32) + (unsigned)ks2;
            lo = 8192 + ((g * 2 + n32) * 2 + ks2) * 512;
        }
        goff[c] = ch * 1024u + (unsigned)lane * 16u;
        ldst[c] = lo;
    }

    // acc chains: 0 = r (gi_r+gh_r merged), 1 = i (merged), 2 = gi_n, 3 = gh_n
    f32x16 acc[4][2];
#pragma unroll
    for (int cid = 0; cid < 4; ++cid)
#pragma unroll
        for (int mf = 0; mf < 2; ++mf)
#pragma unroll
            for (int i = 0; i < 16; ++i) acc[cid][mf][i] = 0.0f;

    const char* wsb = (const char*)ws;
    const int lr = lane & 31, lk8 = (lane >> 5) * 8;

    // prologue: batch 0 -> slab 0 (stays in flight into the loop)
#pragma unroll
    for (int c = 0; c < 10; ++c)
        dma16(wsb + goff[c], &lds[ldst[c]]);

    for (int step = 0; step < 16; ++step) {
        const int cb = (step & 1) * 20480;

        // issue next batch BEFORE waiting on current (counted vmcnt, T4)
        if (step < 15) {
            const unsigned kb = (unsigned)(step + 1) * 2048u;
            const int nb = ((step + 1) & 1) * 20480;
#pragma unroll
            for (int c = 0; c < 10; ++c)
                dma16(wsb + goff[c] + kb, &lds[nb + ldst[c]]);
            asm volatile("s_waitcnt vmcnt(10)" ::: "memory");  // batch(step) done
        } else {
            asm volatile("s_waitcnt vmcnt(0)" ::: "memory");
        }
        __builtin_amdgcn_s_barrier();          // B1: slab[cur] visible to all
        asm volatile("" ::: "memory");
        __builtin_amdgcn_s_setprio(1);

#pragma unroll
        for (int ks2 = 0; ks2 < 2; ++ks2) {
            const int lfo = cb + ks2 * 512 + lk8 * 32 + lr * 8;
            const f16x8 ax0 = *(const f16x8*)&lds[lfo + (mt * 2 + 0) * 1024];
            const f16x8 ax1 = *(const f16x8*)&lds[lfo + (mt * 2 + 1) * 1024];
            const f16x8 ah0 = *(const f16x8*)&lds[lfo + (4 + mt * 2 + 0) * 1024];
            const f16x8 ah1 = *(const f16x8*)&lds[lfo + (4 + mt * 2 + 1) * 1024];
#pragma unroll
            for (int g = 0; g < 6; ++g) {
                const f16x8 bv = *(const f16x8*)&lds[lfo + 8192 + (g * 2 + nt) * 1024];
                const int cid = (g < 3) ? g : (g == 5 ? 3 : g - 3);
                const f16x8 a0 = (g < 3) ? ax0 : ah0;
                const f16x8 a1 = (g < 3) ? ax1 : ah1;
                acc[cid][0] = __builtin_amdgcn_mfma_f32_32x32x16_f16(
                                  a0, bv, acc[cid][0], 0, 0, 0);
                acc[cid][1] = __builtin_amdgcn_mfma_f32_32x32x16_f16(
                                  a1, bv, acc[cid][1], 0, 0, 0);
            }
        }

        __builtin_amdgcn_s_setprio(0);
        asm volatile("" ::: "memory");
        __builtin_amdgcn_s_barrier();          // B2: all done reading slab[cur]
    }

    constexpr float S14 = 16384.0f,     I14 = 1.0f / 16384.0f;
    constexpr float S15 = 32768.0f,     I15 = 1.0f / 32768.0f;

    const int lh = lane >> 5, l32 = lane & 31;
    const int n = n0 + nt * 32 + l32;
    const float brc = bih[n] + bhh[n];                 // merged r bias
    const float bic = bih[n + 512] + bhh[n + 512];     // merged i bias
    const float bnn = bih[n + 1024];
    const float cnn = bhh[n + 1024];

#pragma unroll
    for (int mf = 0; mf < 2; ++mf) {
#pragma unroll
        for (int r = 0; r < 16; ++r) {
            const int row = (r & 3) + 8 * (r >> 2) + 4 * lh;
            const int m   = m0 + mt * 64 + mf * 32 + row;
            const float hv = hid[(size_t)m * Hsz + n];
            const float rg  = qsigmoid_dev(qround(acc[0][mf][r] + brc, S14, I14));
            const float ig  = qsigmoid_dev(qround(acc[1][mf][r] + bic, S14, I14));
            const float gin = qround(acc[2][mf][r] + bnn, S14, I14);
            const float ghn = qround(acc[3][mf][r] + cnn, S14, I14);  // Q27 re-round is identity
            const float rh  = qround(rg * ghn, S15, I15);
            const float ng  = qtanh_dev(rh + gin);
            const float nh  = qround(hv, S15, I15);
            out[(size_t)m * Hsz + n] = ng + ig * (nh - ng);
        }
    }
}

// ---------------- fallback: bf16x3 (used only if ws too small) -------------
__global__ __launch_bounds__(256, 2) void qgru_mfma_bf16x3(
    const float* __restrict__ x, const float* __restrict__ hid,
    const float* __restrict__ wih, const float* __restrict__ whh,
    const float* __restrict__ bih, const float* __restrict__ bhh,
    float* __restrict__ out)
{
    __shared__ __align__(16) unsigned short lds[16384];

    const int t = threadIdx.x, lane = t & 63, wid = t >> 6;
    const int mt = wid >> 1, nt = wid & 1;
    const int m0 = blockIdx.x * BM, n0 = blockIdx.y * BN;
    const int s_r = t >> 2, s_k = (t & 3) << 2;
    const int s_kh = s_k >> 3, s_j = s_k & 7, s_rt = s_r >> 5, s_r32 = s_r & 31;

    const float* gA[2];
    gA[0] = x   + (size_t)(m0 + s_r) * Ksz + s_k;
    gA[1] = hid + (size_t)(m0 + s_r) * Ksz + s_k;
    const float* gW[6];
#pragma unroll
    for (int g = 0; g < 3; ++g) {
        gW[g]     = wih + (size_t)(g * Hsz + n0 + s_r) * Ksz + s_k;
        gW[g + 3] = whh + (size_t)(g * Hsz + n0 + s_r) * Ksz + s_k;
    }
    const int lh = lane >> 5, l32 = lane & 31;

    f32x16 acc[6];
#pragma unroll
    for (int g = 0; g < 6; ++g)
#pragma unroll
        for (int i = 0; i < 16; ++i) acc[g][i] = 0.0f;

    float4 vA[2], vW[6];
#pragma unroll
    for (int tt = 0; tt < 2; ++tt) vA[tt] = *(const float4*)gA[tt];
#pragma unroll
    for (int g = 0; g < 6; ++g)    vW[g]  = *(const float4*)gW[g];

    for (int k0 = 0; k0 < Ksz; k0 += 16) {
        __syncthreads();
#pragma unroll
        for (int tt = 0; tt < 2; ++tt) {
            unsigned h0, h1, l0, l1;
            split2(vA[tt].x, vA[tt].y, h0, l0);
            split2(vA[tt].z, vA[tt].w, h1, l1);
            unsigned bH = ((((tt*2+0)*2+s_rt)*2+s_kh)*32+s_r32)*8 + s_j;
            unsigned bL = ((((tt*2+1)*2+s_rt)*2+s_kh)*32+s_r32)*8 + s_j;
            *reinterpret_cast<uint2*>(&lds[bH]) = make_uint2(h0, h1);
            *reinterpret_cast<uint2*>(&lds[bL]) = make_uint2(l0, l1);
        }
#pragma unroll
        for (int g = 0; g < 6; ++g) {
            unsigned h0, h1, l0, l1;
            split2(vW[g].x, vW[g].y, h0, l0);
            split2(vW[g].z, vW[g].w, h1, l1);
            unsigned bH = 4096u + ((((g*2+0)*2+s_rt)*2+s_kh)*32+s_r32)*8 + s_j;
            unsigned bL = 4096u + ((((g*2+1)*2+s_rt)*2+s_kh)*32+s_r32)*8 + s_j;
            *reinterpret_cast<uint2*>(&lds[bH]) = make_uint2(h0, h1);
            *reinterpret_cast<uint2*>(&lds[bL]) = make_uint2(l0, l1);
        }
        __syncthreads();
        const int kn = (k0 + 16 < Ksz) ? (k0 + 16) : 0;
#pragma unroll
        for (int tt = 0; tt < 2; ++tt) vA[tt] = *(const float4*)(gA[tt] + kn);
#pragma unroll
        for (int g = 0; g < 6; ++g)    vW[g]  = *(const float4*)(gW[g] + kn);

        const bf16x8 ax_hi = *reinterpret_cast<const bf16x8*>(&lds[((((0)*2+mt)*2+lh)*32+l32)*8]);
        const bf16x8 ax_lo = *reinterpret_cast<const bf16x8*>(&lds[((((1)*2+mt)*2+lh)*32+l32)*8]);
        const bf16x8 ah_hi = *reinterpret_cast<const bf16x8*>(&lds[((((2)*2+mt)*2+lh)*32+l32)*8]);
        const bf16x8 ah_lo = *reinterpret_cast<const bf16x8*>(&lds[((((3)*2+mt)*2+lh)*32+l32)*8]);
#pragma unroll
        for (int g = 0; g < 6; ++g) {
            const bf16x8 b_hi = *reinterpret_cast<const bf16x8*>(&lds[4096u + ((((g*2+0)*2+nt)*2+lh)*32+l32)*8]);
            const bf16x8 b_lo = *reinterpret_cast<const bf16x8*>(&lds[4096u + ((((g*2+1)*2+nt)*2+lh)*32+l32)*8]);
            const bf16x8 a_hi = (g < 3) ? ax_hi : ah_hi;
            const bf16x8 a_lo = (g < 3) ? ax_lo : ah_lo;
            acc[g] = __builtin_amdgcn_mfma_f32_32x32x16_bf16(a_hi, b_hi, acc[g], 0, 0, 0);
            acc[g] = __builtin_amdgcn_mfma_f32_32x32x16_bf16(a_hi, b_lo, acc[g], 0, 0, 0);
            acc[g] = __builtin_amdgcn_mfma_f32_32x32x16_bf16(a_lo, b_hi, acc[g], 0, 0, 0);
        }
    }

    constexpr float S14 = 16384.0f,     I14 = 1.0f / 16384.0f;
    constexpr float S15 = 32768.0f,     I15 = 1.0f / 32768.0f;
    constexpr float S27 = 134217728.0f, I27 = 1.0f / 134217728.0f;
    const int n = n0 + nt * 32 + l32;
    const float br = bih[n], bi = bih[n + 512], bn = bih[n + 1024];
    const float cr = bhh[n], ci = bhh[n + 512], cn = bhh[n + 1024];
#pragma unroll
    for (int r = 0; r < 16; ++r) {
        const int row = (r & 3) + 8 * (r >> 2) + 4 * lh;
        const int m   = m0 + mt * 32 + row;
        const float hv = hid[(size_t)m * Hsz + n];
        float gir = qround(acc[0][r] + br, S14, I14);
        float gii = qround(acc[1][r] + bi, S14, I14);
        float gin = qround(acc[2][r] + bn, S14, I14);
        float ghr = qround(acc[3][r] + cr, S14, I14);
        float ghi = qround(acc[4][r] + ci, S14, I14);
        float ghn = qround(acc[5][r] + cn, S14, I14);
        float resetg = qsigmoid_dev(gir + ghr);
        float inputg = qsigmoid_dev(gii + ghi);
        float hn  = qround(ghn, S27, I27);
        float rh  = qround(resetg * hn, S15, I15);
        float newg = qtanh_dev(rh + gin);
        float nh  = qround(hv, S15, I15);
        out[(size_t)m * Hsz + n] = newg + inputg * (nh - newg);
    }
}

extern "C" void kernel_launch(void* const* d_in, const int* in_sizes, int n_in,
                              void* d_out, int out_size, void* d_ws, size_t ws_size,
                              hipStream_t stream) {
    const float* x   = (const float*)d_in[0];
    const float* hid = (const float*)d_in[1];
    const float* wih = (const float*)d_in[2];
    const float* whh = (const float*)d_in[3];
    const float* bih = (const float*)d_in[4];
    const float* bhh = (const float*)d_in[5];
    float* out = (float*)d_out;

    if (ws_size >= WS_NEED) {
        cvt_lds_f16<<<1216, 256, 0, stream>>>(
            x, hid, wih, whh, (_Float16*)d_ws);
        qgru_f16_dma3<<<512, 256, 0, stream>>>(
            (const _Float16*)d_ws, hid, bih, bhh, out);
    } else {
        dim3 grid(Bsz / BM, Hsz / BN);
        qgru_mfma_bf16x3<<<grid, dim3(256), 0, stream>>>(
            x, hid, wih, whh, bih, bhh, out);
    }
}